// Round 11
// baseline (1822.757 us; speedup 1.0000x reference)
//
#include <hip/hip_runtime.h>
#include <hip/hip_fp8.h>
#include <math.h>

#define NN 20000
#define NE 320000
#define NTOT (NE + NN)
#define NBATCH 64
#define HIDW 256
#define NHEADS 8
#define HD 32
#define NL 4
#define BEPS 1e-5f
#define LSLOPE 0.2f
#define WELEMS (128 * HIDW + NL * HIDW * HIDW)  // 294912

typedef __attribute__((ext_vector_type(8))) short s16x8;
typedef __attribute__((ext_vector_type(8))) unsigned short u16x8;
typedef __attribute__((ext_vector_type(4))) float f32x4;
typedef __attribute__((ext_vector_type(2))) unsigned int u32x2;

static __device__ __forceinline__ ushort f2bf(float f) {
  uint u = __float_as_uint(f);
  uint r = (u + 0x7fff + ((u >> 16) & 1)) >> 16;  // RNE
  return (ushort)r;
}
static __device__ __forceinline__ float bf2f(ushort h) {
  return __uint_as_float(((uint)h) << 16);
}
static __device__ __forceinline__ unsigned char fp8e(float f) {
  __hip_fp8_e4m3 t(f);
  return (unsigned char)t.__x;
}
static __device__ __forceinline__ float fp8d(unsigned char v) {
  __hip_fp8_e4m3 t;
  t.__x = (__hip_fp8_storage_t)v;
  return (float)t;
}

// ---------------- CSR scan ----------------
__global__ __launch_bounds__(1024) void k_scan(const int* __restrict__ cnt,
                                               int* __restrict__ rowptr) {
  __shared__ int tsum[1024];
  int tid = threadIdx.x;
  const int per = (NN + 1023) / 1024;  // 20
  int start = tid * per;
  int local = 0;
  for (int j = 0; j < per; ++j) {
    int idx = start + j;
    if (idx < NN) local += cnt[idx];
  }
  tsum[tid] = local;
  __syncthreads();
  for (int off = 1; off < 1024; off <<= 1) {
    int v = (tid >= off) ? tsum[tid - off] : 0;
    __syncthreads();
    tsum[tid] += v;
    __syncthreads();
  }
  int run = (tid == 0) ? 0 : tsum[tid - 1];
  for (int j = 0; j < per; ++j) {
    int idx = start + j;
    if (idx < NN) { rowptr[idx] = run; run += cnt[idx]; }
  }
  if (tid == 1023) rowptr[NN] = tsum[1023];
}

__global__ void k_fill(const int* __restrict__ src, const int* __restrict__ dst,
                       const int* __restrict__ rowptr, int* __restrict__ cur,
                       int* __restrict__ srcs) {
  int i = blockIdx.x * blockDim.x + threadIdx.x;
  if (i >= NTOT) return;
  int s = (i < NE) ? src[i] : (i - NE);
  int d = (i < NE) ? dst[i] : (i - NE);
  int pos = rowptr[d] + atomicAdd(&cur[d], 1);
  srcs[pos] = s;
}

// ---------------- one-time prep: W->bf16 (transposed) + struct_x->bf16 + degree hist ----------------
#define WB ((WELEMS + 255) / 256)            // 1152
#define XB ((NN * 128 / 4 + 255) / 256)      // 2500
#define HB ((NTOT + 255) / 256)              // 1329
__global__ __launch_bounds__(256) void k_prep(const float* __restrict__ projW,
                                              const float* __restrict__ gatW,
                                              const float* __restrict__ sx,
                                              const int* __restrict__ e_dst,
                                              ushort* __restrict__ wh,
                                              ushort* __restrict__ sxh,
                                              int* __restrict__ cnt) {
  int bb = blockIdx.x;
  if (bb < WB) {
    int i = bb * 256 + threadIdx.x;
    if (i >= WELEMS) return;
    float v;
    if (i < 128 * HIDW) {           // proj: [n][128]
      int n = i >> 7, k = i & 127;
      v = projW[k * HIDW + n];
    } else {                        // gat l: [n][256]
      int j = i - 128 * HIDW;
      int l = j >> 16, r = j & 65535;
      int n = r >> 8, k = r & 255;
      v = gatW[l * 65536 + k * HIDW + n];
    }
    wh[i] = f2bf(v);
  } else if (bb < WB + XB) {
    int idx = (bb - WB) * 256 + threadIdx.x;
    if (idx >= NN * 128 / 4) return;
    int i0 = idx * 4;
    float4 v = *reinterpret_cast<const float4*>(&sx[i0]);
    ushort4 hh;
    hh.x = f2bf(v.x); hh.y = f2bf(v.y); hh.z = f2bf(v.z); hh.w = f2bf(v.w);
    *reinterpret_cast<ushort4*>(&sxh[i0]) = hh;
  } else {
    int i = (bb - WB - XB) * 256 + threadIdx.x;
    if (i >= NTOT) return;
    int d = (i < NE) ? e_dst[i] : (i - NE);
    atomicAdd(&cnt[d], 1);
  }
}

// ---------------- MFMA GEMM, plain bf16; optional fused BN-affine+relu on A-load ----------------
// 1D grid 1252, chunked-XCD swizzle (bijective, m204); col-block fastest for A L2 reuse.
#define GBM 64
#define GBN 64
#define GBK 64
#define NWG 1252
#define SWZ_Q 156
#define SWZ_R 4
__global__ __launch_bounds__(256) void k_mfma(const ushort* __restrict__ Ah,
                                              const ushort* __restrict__ Wh,
                                              const float* __restrict__ scshp,
                                              const float* __restrict__ bias,
                                              const float* __restrict__ aS,
                                              const float* __restrict__ aD,
                                              ushort* __restrict__ Co,
                                              unsigned char* __restrict__ Ch8,
                                              float* __restrict__ asrc,
                                              float* __restrict__ adst,
                                              int M, int K, int mode) {
  __shared__ __align__(16) ushort As[GBM][72];  // pad 64->72 (144B stride)
  __shared__ __align__(16) ushort Ws[GBN][72];
  __shared__ float scs[HIDW], shs[HIDW];
  int tid = threadIdx.x;
  if (scshp) {
    scs[tid] = scshp[tid];
    shs[tid] = scshp[HIDW + tid];
  }
  __syncthreads();

  int orig = blockIdx.x;
  int xcd = orig & 7, pos = orig >> 3;
  int wgid = (xcd < SWZ_R ? xcd * (SWZ_Q + 1) : SWZ_R * (SWZ_Q + 1) + (xcd - SWZ_R) * SWZ_Q) + pos;
  int rowblk = wgid >> 2, colblk = wgid & 3;  // col fastest
  int row0 = rowblk * GBM, col0 = colblk * GBN;

  int wid = tid >> 6, lane = tid & 63;
  int wr = wid >> 1, wc = wid & 1;
  int l15 = lane & 15, l4 = lane >> 4;
  f32x4 acc[2][2] = {};
  int sr = tid >> 2;            // row/col 0..63
  int skq = (tid & 3) * 16;     // k offset 0/16/32/48

  for (int k0 = 0; k0 < K; k0 += GBK) {
    int gr = row0 + sr;
    u16x8 va0 = {0,0,0,0,0,0,0,0}, va1 = va0;
    if (gr < M) {
      va0 = *reinterpret_cast<const u16x8*>(&Ah[(size_t)gr * K + k0 + skq]);
      va1 = *reinterpret_cast<const u16x8*>(&Ah[(size_t)gr * K + k0 + skq + 8]);
    }
    if (scshp) {
      int kcs = k0 + skq;
#pragma unroll
      for (int j = 0; j < 8; ++j) {
        va0[j] = (short)f2bf(fmaxf(bf2f((ushort)va0[j]) * scs[kcs + j] + shs[kcs + j], 0.f));
        va1[j] = (short)f2bf(fmaxf(bf2f((ushort)va1[j]) * scs[kcs + 8 + j] + shs[kcs + 8 + j], 0.f));
      }
    }
    u16x8 vw0 = *reinterpret_cast<const u16x8*>(&Wh[(size_t)(col0 + sr) * K + k0 + skq]);
    u16x8 vw1 = *reinterpret_cast<const u16x8*>(&Wh[(size_t)(col0 + sr) * K + k0 + skq + 8]);
    *reinterpret_cast<u16x8*>(&As[sr][skq]) = va0;
    *reinterpret_cast<u16x8*>(&As[sr][skq + 8]) = va1;
    *reinterpret_cast<u16x8*>(&Ws[sr][skq]) = vw0;
    *reinterpret_cast<u16x8*>(&Ws[sr][skq + 8]) = vw1;
    __syncthreads();

#pragma unroll
    for (int ks = 0; ks < 2; ++ks) {
      int ak = ks * 32 + l4 * 8;
      s16x8 af[2], bfv[2];
#pragma unroll
      for (int mf = 0; mf < 2; ++mf)
        af[mf] = *reinterpret_cast<const s16x8*>(&As[wr * 32 + mf * 16 + l15][ak]);
#pragma unroll
      for (int nf = 0; nf < 2; ++nf)
        bfv[nf] = *reinterpret_cast<const s16x8*>(&Ws[wc * 32 + nf * 16 + l15][ak]);
#pragma unroll
      for (int mf = 0; mf < 2; ++mf)
#pragma unroll
        for (int nf = 0; nf < 2; ++nf)
          acc[mf][nf] = __builtin_amdgcn_mfma_f32_16x16x32_bf16(af[mf], bfv[nf], acc[mf][nf], 0, 0, 0);
    }
    __syncthreads();
  }

  // C/D layout (m89-verified): col = lane&15, row = (lane>>4)*4 + reg
  if (mode == 0) {
#pragma unroll
    for (int mf = 0; mf < 2; ++mf)
#pragma unroll
      for (int reg = 0; reg < 4; ++reg) {
        int r = row0 + wr * 32 + mf * 16 + l4 * 4 + reg;
        if (r >= M) continue;
#pragma unroll
        for (int nf = 0; nf < 2; ++nf) {
          int c = col0 + wc * 32 + nf * 16 + l15;
          float v = fmaxf(acc[mf][nf][reg] + bias[c], 0.f);
          Co[(size_t)r * HIDW + c] = f2bf(v);
        }
      }
  } else {
    int hg = colblk * 2 + wc;  // this wave's 32 cols == head hg
    float aSv[2], aDv[2];
#pragma unroll
    for (int nf = 0; nf < 2; ++nf) {
      aSv[nf] = aS[hg * HD + nf * 16 + l15];
      aDv[nf] = aD[hg * HD + nf * 16 + l15];
    }
#pragma unroll
    for (int mf = 0; mf < 2; ++mf)
#pragma unroll
      for (int reg = 0; reg < 4; ++reg) {
        int r = row0 + wr * 32 + mf * 16 + l4 * 4 + reg;
        bool ok = (r < M);
        float pa = 0.f, pd = 0.f;
#pragma unroll
        for (int nf = 0; nf < 2; ++nf) {
          float v = acc[mf][nf][reg];
          if (ok) {
            int c = col0 + wc * 32 + nf * 16 + l15;
            Ch8[(size_t)r * HIDW + c] = fp8e(v);
          }
          pa += v * aSv[nf];
          pd += v * aDv[nf];
        }
        pa += __shfl_xor(pa, 1); pa += __shfl_xor(pa, 2);
        pa += __shfl_xor(pa, 4); pa += __shfl_xor(pa, 8);
        pd += __shfl_xor(pd, 1); pd += __shfl_xor(pd, 2);
        pd += __shfl_xor(pd, 4); pd += __shfl_xor(pd, 8);
        if (ok && l15 == 0) {
          asrc[r * NHEADS + hg] = pa;
          adst[r * NHEADS + hg] = pd;
        }
      }
  }
}

// ---------------- GAT aggregation (fp8 gather) + fused BN stats + last-block BN reduce ----------------
// The final block (atomic done-counter) reduces the 64 stat slices into per-channel
// (scale, shift) -> scsh_out, used by the next layer's mfma A-affine (or by k_pool).
// Deterministic: reduction reads all slices after every block's threadfenced atomics.
__global__ __launch_bounds__(256) void k_agg(const unsigned char* __restrict__ h8,
                                             const int* __restrict__ rowptr,
                                             const int* __restrict__ srcs,
                                             const float* __restrict__ asrc,
                                             const float* __restrict__ adst,
                                             ushort* __restrict__ out,
                                             float* __restrict__ stats64,
                                             const float* __restrict__ g,
                                             const float* __restrict__ b,
                                             float* __restrict__ scsh_out,
                                             int* __restrict__ done) {
  __shared__ float sst[4][512];
  __shared__ int lastFlag;
  int tid = threadIdx.x;
  int wid = tid >> 6, lane = tid & 63;
  int node = blockIdx.x * 4 + wid;  // always < NN
  int el = lane >> 5, sl = lane & 31;
  int c0 = sl * 8, hh = sl >> 2;
  float adn = adst[node * NHEADS + hh];
  int beg = rowptr[node], end = rowptr[node + 1];
  int deg = end - beg;
  float acc[8] = {};
  float ssum = 0.f;
  for (int w0 = 0; w0 < deg; w0 += 64) {
    int sv = srcs[min(beg + w0 + lane, end - 1)];  // deg>=1 (self loop)
    int lim = min(64, deg - w0);
    for (int cb = 0; cb < lim; cb += 16) {
      int s[8];
#pragma unroll
      for (int j = 0; j < 8; ++j) s[j] = __shfl(sv, cb + 2 * j + el);
      float a[8];
      u32x2 hv[8];
#pragma unroll
      for (int j = 0; j < 8; ++j) {
        a[j] = asrc[s[j] * NHEADS + hh];
        hv[j] = *reinterpret_cast<const u32x2*>(&h8[(size_t)s[j] * HIDW + c0]);
      }
#pragma unroll
      for (int j = 0; j < 8; ++j) {
        float e = a[j] + adn;
        e = (e >= 0.f) ? e : LSLOPE * e;
        float ex = ((cb + 2 * j + el) < lim) ? __expf(e) : 0.f;  // logits O(1): no max-subtr
        ssum += ex;
        union { u32x2 v; unsigned char bch[8]; } U;
        U.v = hv[j];
#pragma unroll
        for (int q = 0; q < 8; ++q) acc[q] += ex * fp8d(U.bch[q]);
      }
    }
  }
  ssum += __shfl_xor(ssum, 32);
#pragma unroll
  for (int q = 0; q < 8; ++q) acc[q] += __shfl_xor(acc[q], 32);
  if (el == 0) {
    float inv = 1.f / ssum;
    u16x8 o;
    float of[8];
#pragma unroll
    for (int q = 0; q < 8; ++q) {
      of[q] = acc[q] * inv;
      o[q] = f2bf(of[q]);
    }
    *reinterpret_cast<u16x8*>(&out[(size_t)node * HIDW + c0]) = o;
#pragma unroll
    for (int q = 0; q < 8; ++q) {
      sst[wid][c0 + q] = of[q];
      sst[wid][256 + c0 + q] = of[q] * of[q];
    }
  }
  __syncthreads();
  int c = tid;
  float s = sst[0][c] + sst[1][c] + sst[2][c] + sst[3][c];
  float s2 = sst[0][256 + c] + sst[1][256 + c] + sst[2][256 + c] + sst[3][256 + c];
  float* slice = stats64 + (size_t)(blockIdx.x & 63) * 512;
  atomicAdd(&slice[c], s);
  atomicAdd(&slice[256 + c], s2);
  // ---- last block: reduce slices -> (scale, shift) ----
  __threadfence();
  if (tid == 0) lastFlag = (atomicAdd(done, 1) == (int)gridDim.x - 1);
  __syncthreads();
  if (lastFlag) {
    float st = 0.f, st2 = 0.f;
    for (int i = 0; i < 64; ++i) {
      st += stats64[(size_t)i * 512 + c];
      st2 += stats64[(size_t)i * 512 + 256 + c];
    }
    float mean = st * (1.f / NN);
    float var = fmaxf(st2 * (1.f / NN) - mean * mean, 0.f);
    float sc = g[c] * rsqrtf(var + BEPS);
    scsh_out[c] = sc;
    scsh_out[HIDW + c] = b[c] - mean * sc;
  }
}

// ---------------- mean pool (BN affine from precomputed scsh; sorted batch) ----------------
__global__ __launch_bounds__(256) void k_pool(const ushort* __restrict__ x,
                                              const float* __restrict__ scsh,
                                              const int* __restrict__ batch,
                                              float* __restrict__ pool,
                                              int* __restrict__ pcnt) {
  int c = threadIdx.x;
  float sc = scsh[c], sh = scsh[HIDW + c];
  const int RPB = (NN + 255) / 256;  // 79
  int r0 = blockIdx.x * RPB, r1 = min(r0 + RPB, NN);
  if (r0 >= r1) return;
  int curb = batch[r0];
  float acc = 0.f;
  int run = 0;
  for (int r = r0; r < r1; ++r) {
    int bb = batch[r];
    if (bb != curb) {
      atomicAdd(&pool[curb * HIDW + c], acc);
      if (c == 0) atomicAdd(&pcnt[curb], run);
      acc = 0.f; run = 0; curb = bb;
    }
    float v = fmaxf(bf2f(x[(size_t)r * HIDW + c]) * sc + sh, 0.f);
    acc += v;
    run++;
  }
  atomicAdd(&pool[curb * HIDW + c], acc);
  if (c == 0) atomicAdd(&pcnt[curb], run);
}

// ---------------- whole head in one kernel (B=64 blocks) ----------------
__global__ __launch_bounds__(256) void k_head(const float* __restrict__ pool,
                                              const int* __restrict__ pcnt,
                                              const float* __restrict__ Wv, const float* __restrict__ bv,
                                              const float* __restrict__ Wo, const float* __restrict__ bo,
                                              const float* __restrict__ fusW, const float* __restrict__ fusB,
                                              const float* __restrict__ p1W, const float* __restrict__ p1b,
                                              const float* __restrict__ p2W, const float* __restrict__ p2b,
                                              float* __restrict__ out) {
  __shared__ float pr[HIDW], sA[HIDW], sB[HIDW], sH[128];
  int b = blockIdx.x, c = threadIdx.x;
  float invc = 1.f / fmaxf((float)pcnt[b], 1.f);
  pr[c] = pool[b * HIDW + c] * invc;
  __syncthreads();
  float acc = bv[c];
  for (int k = 0; k < HIDW; ++k) acc += pr[k] * Wv[k * HIDW + c];
  sA[c] = acc;
  __syncthreads();
  acc = bo[c];
  for (int k = 0; k < HIDW; ++k) acc += sA[k] * Wo[k * HIDW + c];
  sB[c] = acc;
  __syncthreads();
  acc = fusB[c];
  for (int k = 0; k < HIDW; ++k) acc += sB[k] * fusW[k * HIDW + c];
  for (int k = 0; k < HIDW; ++k) acc += pr[k] * fusW[(HIDW + k) * HIDW + c];
  float xf = fmaxf(acc, 0.f);
  __syncthreads();
  sA[c] = xf;
  __syncthreads();
  if (c < 128) {
    acc = p1b[c];
    for (int k = 0; k < HIDW; ++k) acc += sA[k] * p1W[k * 128 + c];
    sH[c] = fmaxf(acc, 0.f);
  }
  __syncthreads();
  if (c == 0) {
    float s = p2b[0];
    for (int k = 0; k < 128; ++k) s += sH[k] * p2W[k];
    out[b] = s;
  }
}

// ---------------- launch ----------------
extern "C" void kernel_launch(void* const* d_in, const int* in_sizes, int n_in,
                              void* d_out, int out_size, void* d_ws, size_t ws_size,
                              hipStream_t stream) {
  // seq branch + Wq/bq/Wk/bk are dead code (softmax over singleton axis == 1).
  // gat_b cancels inside BatchNorm.
  const float* struct_x = (const float*)d_in[1];
  const int* edge = (const int*)d_in[3];
  const int* batch = (const int*)d_in[5];
  const float* projW = (const float*)d_in[12];
  const float* projB = (const float*)d_in[13];
  const float* gatW = (const float*)d_in[14];
  const float* attS = (const float*)d_in[15];
  const float* attD = (const float*)d_in[16];
  const float* bnG = (const float*)d_in[18];
  const float* bnB = (const float*)d_in[19];
  const float* Wv = (const float*)d_in[24];
  const float* bv = (const float*)d_in[25];
  const float* Wo = (const float*)d_in[26];
  const float* bo = (const float*)d_in[27];
  const float* fusW = (const float*)d_in[28];
  const float* fusB = (const float*)d_in[29];
  const float* p1W = (const float*)d_in[30];
  const float* p1b = (const float*)d_in[31];
  const float* p2W = (const float*)d_in[32];
  const float* p2b = (const float*)d_in[33];
  float* out = (float*)d_out;

  const int* e_src = edge;
  const int* e_dst = edge + NE;

  char* ws = (char*)d_ws;
  size_t off = 0;
  auto alloc = [&](size_t bytes) -> void* {
    void* p = ws + off;
    off = (off + bytes + 255) & ~(size_t)255;
    return p;
  };
  ushort* buf0 = (ushort*)alloc((size_t)NN * HIDW * 2);        // bf16 agg output
  unsigned char* hb8 = (unsigned char*)alloc((size_t)NN * HIDW);  // fp8 h for gather
  ushort* a0 = (ushort*)alloc((size_t)NN * HIDW * 2);          // bf16 proj output
  ushort* sxh = (ushort*)alloc((size_t)NN * 128 * 2);          // bf16 struct_x
  ushort* wth = (ushort*)alloc((size_t)WELEMS * 2);            // bf16 W [n][k]
  int* rowptr = (int*)alloc((NN + 1) * 4);
  int* srcs = (int*)alloc((size_t)NTOT * 4);
  float* asrc = (float*)alloc((size_t)NN * NHEADS * 4);
  float* adst = (float*)alloc((size_t)NN * NHEADS * 4);
  float* scsh = (float*)alloc((size_t)NL * 512 * 4);           // per-layer (scale, shift)
  // ---- zero-init region (single memset, every call) ----
  char* zero_base = ws + off;
  int* cnt = (int*)alloc(NN * 4);
  int* cur = (int*)alloc(NN * 4);
  float* stats64 = (float*)alloc((size_t)NL * 64 * 512 * 4);   // per-layer sliced stats
  int* done = (int*)alloc(NL * 4);                             // last-block counters
  float* pool = (float*)alloc(NBATCH * HIDW * 4);
  int* pcnt = (int*)alloc(NBATCH * 4);
  size_t zero_bytes = (ws + off) - zero_base;

  const int TPB = 256;
  const int gEdge = (NTOT + TPB - 1) / TPB;

  hipMemsetAsync(zero_base, 0, zero_bytes, stream);

  // ---- prep (W cast + struct_x cast + degree hist, merged) ----
  k_prep<<<WB + XB + HB, TPB, 0, stream>>>(projW, gatW, struct_x, e_dst, wth, sxh, cnt);
  k_scan<<<1, 1024, 0, stream>>>(cnt, rowptr);
  k_fill<<<gEdge, TPB, 0, stream>>>(e_src, e_dst, rowptr, cur, srcs);

  // proj: a0 = bf16(relu(struct_x @ projW + projB))
  k_mfma<<<NWG, 256, 0, stream>>>(sxh, wth, nullptr, projB, nullptr, nullptr,
                                  a0, nullptr, nullptr, nullptr, NN, 128, 0);

  for (int l = 0; l < NL; ++l) {
    const ushort* whL = wth + 128 * HIDW + (size_t)l * HIDW * HIDW;
    float* s64 = stats64 + (size_t)l * 64 * 512;
    k_mfma<<<NWG, 256, 0, stream>>>((l == 0) ? a0 : buf0, whL,
                                    (l == 0) ? nullptr : scsh + (l - 1) * 512, nullptr,
                                    attS + l * HIDW, attD + l * HIDW,
                                    nullptr, hb8, asrc, adst, NN, HIDW, 1);
    k_agg<<<NN / 4, 256, 0, stream>>>(hb8, rowptr, srcs, asrc, adst, buf0, s64,
                                      bnG + l * HIDW, bnB + l * HIDW,
                                      scsh + l * 512, done + l);
  }

  // ---- mean pool (layer-3 BN affine + relu via precomputed scsh) ----
  k_pool<<<256, 256, 0, stream>>>(buf0, scsh + 3 * 512, batch, pool, pcnt);

  // ---- head ----
  k_head<<<NBATCH, 256, 0, stream>>>(pool, pcnt, Wv, bv, Wo, bo, fusW, fusB,
                                     p1W, p1b, p2W, p2b, out);
}

// Round 12
// 317.068 us; speedup vs baseline: 5.7488x; 5.7488x over previous
//
#include <hip/hip_runtime.h>
#include <hip/hip_fp8.h>
#include <math.h>

#define NN 20000
#define NE 320000
#define NTOT (NE + NN)
#define NBATCH 64
#define HIDW 256
#define NHEADS 8
#define HD 32
#define NL 4
#define BEPS 1e-5f
#define LSLOPE 0.2f
#define WELEMS (128 * HIDW + NL * HIDW * HIDW)  // 294912

typedef __attribute__((ext_vector_type(8))) short s16x8;
typedef __attribute__((ext_vector_type(8))) unsigned short u16x8;
typedef __attribute__((ext_vector_type(4))) float f32x4;
typedef __attribute__((ext_vector_type(2))) unsigned int u32x2;

static __device__ __forceinline__ ushort f2bf(float f) {
  uint u = __float_as_uint(f);
  uint r = (u + 0x7fff + ((u >> 16) & 1)) >> 16;  // RNE
  return (ushort)r;
}
static __device__ __forceinline__ float bf2f(ushort h) {
  return __uint_as_float(((uint)h) << 16);
}
static __device__ __forceinline__ unsigned char fp8e(float f) {
  __hip_fp8_e4m3 t(f);
  return (unsigned char)t.__x;
}
static __device__ __forceinline__ float fp8d(unsigned char v) {
  __hip_fp8_e4m3 t;
  t.__x = (__hip_fp8_storage_t)v;
  return (float)t;
}

// ---------------- CSR scan ----------------
__global__ __launch_bounds__(1024) void k_scan(const int* __restrict__ cnt,
                                               int* __restrict__ rowptr) {
  __shared__ int tsum[1024];
  int tid = threadIdx.x;
  const int per = (NN + 1023) / 1024;  // 20
  int start = tid * per;
  int local = 0;
  for (int j = 0; j < per; ++j) {
    int idx = start + j;
    if (idx < NN) local += cnt[idx];
  }
  tsum[tid] = local;
  __syncthreads();
  for (int off = 1; off < 1024; off <<= 1) {
    int v = (tid >= off) ? tsum[tid - off] : 0;
    __syncthreads();
    tsum[tid] += v;
    __syncthreads();
  }
  int run = (tid == 0) ? 0 : tsum[tid - 1];
  for (int j = 0; j < per; ++j) {
    int idx = start + j;
    if (idx < NN) { rowptr[idx] = run; run += cnt[idx]; }
  }
  if (tid == 1023) rowptr[NN] = tsum[1023];
}

__global__ void k_fill(const int* __restrict__ src, const int* __restrict__ dst,
                       const int* __restrict__ rowptr, int* __restrict__ cur,
                       int* __restrict__ srcs) {
  int i = blockIdx.x * blockDim.x + threadIdx.x;
  if (i >= NTOT) return;
  int s = (i < NE) ? src[i] : (i - NE);
  int d = (i < NE) ? dst[i] : (i - NE);
  int pos = rowptr[d] + atomicAdd(&cur[d], 1);
  srcs[pos] = s;
}

// ---------------- one-time prep: W->bf16 (transposed) + struct_x->bf16 + degree hist ----------------
#define WB ((WELEMS + 255) / 256)            // 1152
#define XB ((NN * 128 / 4 + 255) / 256)      // 2500
#define HB ((NTOT + 255) / 256)              // 1329
__global__ __launch_bounds__(256) void k_prep(const float* __restrict__ projW,
                                              const float* __restrict__ gatW,
                                              const float* __restrict__ sx,
                                              const int* __restrict__ e_dst,
                                              ushort* __restrict__ wh,
                                              ushort* __restrict__ sxh,
                                              int* __restrict__ cnt) {
  int bb = blockIdx.x;
  if (bb < WB) {
    int i = bb * 256 + threadIdx.x;
    if (i >= WELEMS) return;
    float v;
    if (i < 128 * HIDW) {           // proj: [n][128]
      int n = i >> 7, k = i & 127;
      v = projW[k * HIDW + n];
    } else {                        // gat l: [n][256]
      int j = i - 128 * HIDW;
      int l = j >> 16, r = j & 65535;
      int n = r >> 8, k = r & 255;
      v = gatW[l * 65536 + k * HIDW + n];
    }
    wh[i] = f2bf(v);
  } else if (bb < WB + XB) {
    int idx = (bb - WB) * 256 + threadIdx.x;
    if (idx >= NN * 128 / 4) return;
    int i0 = idx * 4;
    float4 v = *reinterpret_cast<const float4*>(&sx[i0]);
    ushort4 hh;
    hh.x = f2bf(v.x); hh.y = f2bf(v.y); hh.z = f2bf(v.z); hh.w = f2bf(v.w);
    *reinterpret_cast<ushort4*>(&sxh[i0]) = hh;
  } else {
    int i = (bb - WB - XB) * 256 + threadIdx.x;
    if (i >= NTOT) return;
    int d = (i < NE) ? e_dst[i] : (i - NE);
    atomicAdd(&cnt[d], 1);
  }
}

// ---------------- reduce sliced BN stats -> per-channel (scale, shift) ----------------
__global__ __launch_bounds__(256) void k_red(const float* __restrict__ stats64,
                                             const float* __restrict__ g,
                                             const float* __restrict__ b,
                                             float* __restrict__ scsh) {
  int c = threadIdx.x;
  float st = 0.f, st2 = 0.f;
  for (int i = 0; i < 64; ++i) {
    st += stats64[(size_t)i * 512 + c];
    st2 += stats64[(size_t)i * 512 + 256 + c];
  }
  float mean = st * (1.f / NN);
  float var = fmaxf(st2 * (1.f / NN) - mean * mean, 0.f);
  float sc = g[c] * rsqrtf(var + BEPS);
  scsh[c] = sc;
  scsh[HIDW + c] = b[c] - mean * sc;
}

// ---------------- MFMA GEMM, plain bf16; optional fused BN-affine+relu on A-load ----------------
// 1D grid 1252, chunked-XCD swizzle (bijective, m204); col-block fastest for A L2 reuse.
#define GBM 64
#define GBN 64
#define GBK 64
#define NWG 1252
#define SWZ_Q 156
#define SWZ_R 4
__global__ __launch_bounds__(256) void k_mfma(const ushort* __restrict__ Ah,
                                              const ushort* __restrict__ Wh,
                                              const float* __restrict__ scshp,
                                              const float* __restrict__ bias,
                                              const float* __restrict__ aS,
                                              const float* __restrict__ aD,
                                              ushort* __restrict__ Co,
                                              unsigned char* __restrict__ Ch8,
                                              float* __restrict__ asrc,
                                              float* __restrict__ adst,
                                              int M, int K, int mode) {
  __shared__ __align__(16) ushort As[GBM][72];  // pad 64->72 (144B stride)
  __shared__ __align__(16) ushort Ws[GBN][72];
  __shared__ float scs[HIDW], shs[HIDW];
  int tid = threadIdx.x;
  if (scshp) {
    scs[tid] = scshp[tid];
    shs[tid] = scshp[HIDW + tid];
  }
  __syncthreads();

  int orig = blockIdx.x;
  int xcd = orig & 7, pos = orig >> 3;
  int wgid = (xcd < SWZ_R ? xcd * (SWZ_Q + 1) : SWZ_R * (SWZ_Q + 1) + (xcd - SWZ_R) * SWZ_Q) + pos;
  int rowblk = wgid >> 2, colblk = wgid & 3;  // col fastest
  int row0 = rowblk * GBM, col0 = colblk * GBN;

  int wid = tid >> 6, lane = tid & 63;
  int wr = wid >> 1, wc = wid & 1;
  int l15 = lane & 15, l4 = lane >> 4;
  f32x4 acc[2][2] = {};
  int sr = tid >> 2;            // row/col 0..63
  int skq = (tid & 3) * 16;     // k offset 0/16/32/48

  for (int k0 = 0; k0 < K; k0 += GBK) {
    int gr = row0 + sr;
    u16x8 va0 = {0,0,0,0,0,0,0,0}, va1 = va0;
    if (gr < M) {
      va0 = *reinterpret_cast<const u16x8*>(&Ah[(size_t)gr * K + k0 + skq]);
      va1 = *reinterpret_cast<const u16x8*>(&Ah[(size_t)gr * K + k0 + skq + 8]);
    }
    if (scshp) {
      int kcs = k0 + skq;
#pragma unroll
      for (int j = 0; j < 8; ++j) {
        va0[j] = (short)f2bf(fmaxf(bf2f((ushort)va0[j]) * scs[kcs + j] + shs[kcs + j], 0.f));
        va1[j] = (short)f2bf(fmaxf(bf2f((ushort)va1[j]) * scs[kcs + 8 + j] + shs[kcs + 8 + j], 0.f));
      }
    }
    u16x8 vw0 = *reinterpret_cast<const u16x8*>(&Wh[(size_t)(col0 + sr) * K + k0 + skq]);
    u16x8 vw1 = *reinterpret_cast<const u16x8*>(&Wh[(size_t)(col0 + sr) * K + k0 + skq + 8]);
    *reinterpret_cast<u16x8*>(&As[sr][skq]) = va0;
    *reinterpret_cast<u16x8*>(&As[sr][skq + 8]) = va1;
    *reinterpret_cast<u16x8*>(&Ws[sr][skq]) = vw0;
    *reinterpret_cast<u16x8*>(&Ws[sr][skq + 8]) = vw1;
    __syncthreads();

#pragma unroll
    for (int ks = 0; ks < 2; ++ks) {
      int ak = ks * 32 + l4 * 8;
      s16x8 af[2], bfv[2];
#pragma unroll
      for (int mf = 0; mf < 2; ++mf)
        af[mf] = *reinterpret_cast<const s16x8*>(&As[wr * 32 + mf * 16 + l15][ak]);
#pragma unroll
      for (int nf = 0; nf < 2; ++nf)
        bfv[nf] = *reinterpret_cast<const s16x8*>(&Ws[wc * 32 + nf * 16 + l15][ak]);
#pragma unroll
      for (int mf = 0; mf < 2; ++mf)
#pragma unroll
        for (int nf = 0; nf < 2; ++nf)
          acc[mf][nf] = __builtin_amdgcn_mfma_f32_16x16x32_bf16(af[mf], bfv[nf], acc[mf][nf], 0, 0, 0);
    }
    __syncthreads();
  }

  // C/D layout (m89-verified): col = lane&15, row = (lane>>4)*4 + reg
  if (mode == 0) {
#pragma unroll
    for (int mf = 0; mf < 2; ++mf)
#pragma unroll
      for (int reg = 0; reg < 4; ++reg) {
        int r = row0 + wr * 32 + mf * 16 + l4 * 4 + reg;
        if (r >= M) continue;
#pragma unroll
        for (int nf = 0; nf < 2; ++nf) {
          int c = col0 + wc * 32 + nf * 16 + l15;
          float v = fmaxf(acc[mf][nf][reg] + bias[c], 0.f);
          Co[(size_t)r * HIDW + c] = f2bf(v);
        }
      }
  } else {
    int hg = colblk * 2 + wc;  // this wave's 32 cols == head hg
    float aSv[2], aDv[2];
#pragma unroll
    for (int nf = 0; nf < 2; ++nf) {
      aSv[nf] = aS[hg * HD + nf * 16 + l15];
      aDv[nf] = aD[hg * HD + nf * 16 + l15];
    }
#pragma unroll
    for (int mf = 0; mf < 2; ++mf)
#pragma unroll
      for (int reg = 0; reg < 4; ++reg) {
        int r = row0 + wr * 32 + mf * 16 + l4 * 4 + reg;
        bool ok = (r < M);
        float pa = 0.f, pd = 0.f;
#pragma unroll
        for (int nf = 0; nf < 2; ++nf) {
          float v = acc[mf][nf][reg];
          if (ok) {
            int c = col0 + wc * 32 + nf * 16 + l15;
            Ch8[(size_t)r * HIDW + c] = fp8e(v);
          }
          pa += v * aSv[nf];
          pd += v * aDv[nf];
        }
        pa += __shfl_xor(pa, 1); pa += __shfl_xor(pa, 2);
        pa += __shfl_xor(pa, 4); pa += __shfl_xor(pa, 8);
        pd += __shfl_xor(pd, 1); pd += __shfl_xor(pd, 2);
        pd += __shfl_xor(pd, 4); pd += __shfl_xor(pd, 8);
        if (ok && l15 == 0) {
          asrc[r * NHEADS + hg] = pa;
          adst[r * NHEADS + hg] = pd;
        }
      }
  }
}

// ---------------- GAT aggregation (fp8 gather payload) + fused BN stats ----------------
__global__ __launch_bounds__(256) void k_agg(const unsigned char* __restrict__ h8,
                                             const int* __restrict__ rowptr,
                                             const int* __restrict__ srcs,
                                             const float* __restrict__ asrc,
                                             const float* __restrict__ adst,
                                             ushort* __restrict__ out,
                                             float* __restrict__ stats64) {
  __shared__ float sst[4][512];
  int tid = threadIdx.x;
  int wid = tid >> 6, lane = tid & 63;
  int node = blockIdx.x * 4 + wid;  // always < NN
  int el = lane >> 5, sl = lane & 31;
  int c0 = sl * 8, hh = sl >> 2;
  float adn = adst[node * NHEADS + hh];
  int beg = rowptr[node], end = rowptr[node + 1];
  int deg = end - beg;
  float acc[8] = {};
  float ssum = 0.f;
  for (int w0 = 0; w0 < deg; w0 += 64) {
    int sv = srcs[min(beg + w0 + lane, end - 1)];  // deg>=1 (self loop)
    int lim = min(64, deg - w0);
    for (int cb = 0; cb < lim; cb += 16) {
      int s[8];
#pragma unroll
      for (int j = 0; j < 8; ++j) s[j] = __shfl(sv, cb + 2 * j + el);
      float a[8];
      u32x2 hv[8];
#pragma unroll
      for (int j = 0; j < 8; ++j) {
        a[j] = asrc[s[j] * NHEADS + hh];
        hv[j] = *reinterpret_cast<const u32x2*>(&h8[(size_t)s[j] * HIDW + c0]);
      }
#pragma unroll
      for (int j = 0; j < 8; ++j) {
        float e = a[j] + adn;
        e = (e >= 0.f) ? e : LSLOPE * e;
        float ex = ((cb + 2 * j + el) < lim) ? __expf(e) : 0.f;  // logits O(1): no max-subtr
        ssum += ex;
        union { u32x2 v; unsigned char b[8]; } U;
        U.v = hv[j];
#pragma unroll
        for (int q = 0; q < 8; ++q) acc[q] += ex * fp8d(U.b[q]);
      }
    }
  }
  ssum += __shfl_xor(ssum, 32);
#pragma unroll
  for (int q = 0; q < 8; ++q) acc[q] += __shfl_xor(acc[q], 32);
  if (el == 0) {
    float inv = 1.f / ssum;
    u16x8 o;
    float of[8];
#pragma unroll
    for (int q = 0; q < 8; ++q) {
      of[q] = acc[q] * inv;
      o[q] = f2bf(of[q]);
    }
    *reinterpret_cast<u16x8*>(&out[(size_t)node * HIDW + c0]) = o;
#pragma unroll
    for (int q = 0; q < 8; ++q) {
      sst[wid][c0 + q] = of[q];
      sst[wid][256 + c0 + q] = of[q] * of[q];
    }
  }
  __syncthreads();
  int c = tid;
  float s = sst[0][c] + sst[1][c] + sst[2][c] + sst[3][c];
  float s2 = sst[0][256 + c] + sst[1][256 + c] + sst[2][256 + c] + sst[3][256 + c];
  float* slice = stats64 + (size_t)(blockIdx.x & 63) * 512;
  atomicAdd(&slice[c], s);
  atomicAdd(&slice[256 + c], s2);
}

// ---------------- mean pool (fused layer-3 BN from sliced stats; sorted batch) ----------------
__global__ __launch_bounds__(256) void k_pool(const ushort* __restrict__ x,
                                              const float* __restrict__ stats64,
                                              const float* __restrict__ g,
                                              const float* __restrict__ b,
                                              const int* __restrict__ batch,
                                              float* __restrict__ pool,
                                              int* __restrict__ pcnt) {
  int c = threadIdx.x;
  float st = 0.f, st2 = 0.f;
  for (int i = 0; i < 64; ++i) {
    st += stats64[(size_t)i * 512 + c];
    st2 += stats64[(size_t)i * 512 + 256 + c];
  }
  float mean = st * (1.f / NN);
  float var = fmaxf(st2 * (1.f / NN) - mean * mean, 0.f);
  float sc = g[c] * rsqrtf(var + BEPS);
  float sh = b[c] - mean * sc;
  const int RPB = (NN + 255) / 256;  // 79
  int r0 = blockIdx.x * RPB, r1 = min(r0 + RPB, NN);
  if (r0 >= r1) return;
  int curb = batch[r0];
  float acc = 0.f;
  int run = 0;
  for (int r = r0; r < r1; ++r) {
    int bb = batch[r];
    if (bb != curb) {
      atomicAdd(&pool[curb * HIDW + c], acc);
      if (c == 0) atomicAdd(&pcnt[curb], run);
      acc = 0.f; run = 0; curb = bb;
    }
    float v = fmaxf(bf2f(x[(size_t)r * HIDW + c]) * sc + sh, 0.f);
    acc += v;
    run++;
  }
  atomicAdd(&pool[curb * HIDW + c], acc);
  if (c == 0) atomicAdd(&pcnt[curb], run);
}

// ---------------- whole head in one kernel (B=64 blocks) ----------------
__global__ __launch_bounds__(256) void k_head(const float* __restrict__ pool,
                                              const int* __restrict__ pcnt,
                                              const float* __restrict__ Wv, const float* __restrict__ bv,
                                              const float* __restrict__ Wo, const float* __restrict__ bo,
                                              const float* __restrict__ fusW, const float* __restrict__ fusB,
                                              const float* __restrict__ p1W, const float* __restrict__ p1b,
                                              const float* __restrict__ p2W, const float* __restrict__ p2b,
                                              float* __restrict__ out) {
  __shared__ float pr[HIDW], sA[HIDW], sB[HIDW], sH[128];
  int b = blockIdx.x, c = threadIdx.x;
  float invc = 1.f / fmaxf((float)pcnt[b], 1.f);
  pr[c] = pool[b * HIDW + c] * invc;
  __syncthreads();
  float acc = bv[c];
  for (int k = 0; k < HIDW; ++k) acc += pr[k] * Wv[k * HIDW + c];
  sA[c] = acc;
  __syncthreads();
  acc = bo[c];
  for (int k = 0; k < HIDW; ++k) acc += sA[k] * Wo[k * HIDW + c];
  sB[c] = acc;
  __syncthreads();
  acc = fusB[c];
  for (int k = 0; k < HIDW; ++k) acc += sB[k] * fusW[k * HIDW + c];
  for (int k = 0; k < HIDW; ++k) acc += pr[k] * fusW[(HIDW + k) * HIDW + c];
  float xf = fmaxf(acc, 0.f);
  __syncthreads();
  sA[c] = xf;
  __syncthreads();
  if (c < 128) {
    acc = p1b[c];
    for (int k = 0; k < HIDW; ++k) acc += sA[k] * p1W[k * 128 + c];
    sH[c] = fmaxf(acc, 0.f);
  }
  __syncthreads();
  if (c == 0) {
    float s = p2b[0];
    for (int k = 0; k < 128; ++k) s += sH[k] * p2W[k];
    out[b] = s;
  }
}

// ---------------- launch ----------------
extern "C" void kernel_launch(void* const* d_in, const int* in_sizes, int n_in,
                              void* d_out, int out_size, void* d_ws, size_t ws_size,
                              hipStream_t stream) {
  // seq branch + Wq/bq/Wk/bk are dead code (softmax over singleton axis == 1).
  // gat_b cancels inside BatchNorm.
  const float* struct_x = (const float*)d_in[1];
  const int* edge = (const int*)d_in[3];
  const int* batch = (const int*)d_in[5];
  const float* projW = (const float*)d_in[12];
  const float* projB = (const float*)d_in[13];
  const float* gatW = (const float*)d_in[14];
  const float* attS = (const float*)d_in[15];
  const float* attD = (const float*)d_in[16];
  const float* bnG = (const float*)d_in[18];
  const float* bnB = (const float*)d_in[19];
  const float* Wv = (const float*)d_in[24];
  const float* bv = (const float*)d_in[25];
  const float* Wo = (const float*)d_in[26];
  const float* bo = (const float*)d_in[27];
  const float* fusW = (const float*)d_in[28];
  const float* fusB = (const float*)d_in[29];
  const float* p1W = (const float*)d_in[30];
  const float* p1b = (const float*)d_in[31];
  const float* p2W = (const float*)d_in[32];
  const float* p2b = (const float*)d_in[33];
  float* out = (float*)d_out;

  const int* e_src = edge;
  const int* e_dst = edge + NE;

  char* ws = (char*)d_ws;
  size_t off = 0;
  auto alloc = [&](size_t bytes) -> void* {
    void* p = ws + off;
    off = (off + bytes + 255) & ~(size_t)255;
    return p;
  };
  ushort* buf0 = (ushort*)alloc((size_t)NN * HIDW * 2);        // bf16 agg output
  unsigned char* hb8 = (unsigned char*)alloc((size_t)NN * HIDW);  // fp8 h for gather
  ushort* a0 = (ushort*)alloc((size_t)NN * HIDW * 2);          // bf16 proj output
  ushort* sxh = (ushort*)alloc((size_t)NN * 128 * 2);          // bf16 struct_x
  ushort* wth = (ushort*)alloc((size_t)WELEMS * 2);            // bf16 W [n][k]
  int* rowptr = (int*)alloc((NN + 1) * 4);
  int* srcs = (int*)alloc((size_t)NTOT * 4);
  float* asrc = (float*)alloc((size_t)NN * NHEADS * 4);
  float* adst = (float*)alloc((size_t)NN * NHEADS * 4);
  float* scsh = (float*)alloc(512 * 4);
  // ---- zero-init region (single memset) ----
  char* zero_base = ws + off;
  int* cnt = (int*)alloc(NN * 4);
  int* cur = (int*)alloc(NN * 4);
  float* stats64 = (float*)alloc((size_t)NL * 64 * 512 * 4);  // per-layer sliced stats
  float* pool = (float*)alloc(NBATCH * HIDW * 4);
  int* pcnt = (int*)alloc(NBATCH * 4);
  size_t zero_bytes = (ws + off) - zero_base;

  const int TPB = 256;
  const int gEdge = (NTOT + TPB - 1) / TPB;

  hipMemsetAsync(zero_base, 0, zero_bytes, stream);

  // ---- prep (W cast + struct_x cast + degree hist, merged) ----
  k_prep<<<WB + XB + HB, TPB, 0, stream>>>(projW, gatW, struct_x, e_dst, wth, sxh, cnt);
  k_scan<<<1, 1024, 0, stream>>>(cnt, rowptr);
  k_fill<<<gEdge, TPB, 0, stream>>>(e_src, e_dst, rowptr, cur, srcs);

  // proj: a0 = bf16(relu(struct_x @ projW + projB))
  k_mfma<<<NWG, 256, 0, stream>>>(sxh, wth, nullptr, projB, nullptr, nullptr,
                                  a0, nullptr, nullptr, nullptr, NN, 128, 0);

  for (int l = 0; l < NL; ++l) {
    const ushort* whL = wth + 128 * HIDW + (size_t)l * HIDW * HIDW;
    float* s64 = stats64 + (size_t)l * 64 * 512;
    if (l > 0) {
      // BN(l-1) coefficients for this layer's fused A-affine
      k_red<<<1, 256, 0, stream>>>(stats64 + (size_t)(l - 1) * 64 * 512,
                                   bnG + (l - 1) * HIDW, bnB + (l - 1) * HIDW, scsh);
    }
    k_mfma<<<NWG, 256, 0, stream>>>((l == 0) ? a0 : buf0, whL,
                                    (l == 0) ? nullptr : scsh, nullptr,
                                    attS + l * HIDW, attD + l * HIDW,
                                    nullptr, hb8, asrc, adst, NN, HIDW, 1);
    k_agg<<<NN / 4, 256, 0, stream>>>(hb8, rowptr, srcs, asrc, adst, buf0, s64);
  }

  // ---- mean pool (fused layer-3 BN affine + relu from sliced stats) ----
  k_pool<<<256, 256, 0, stream>>>(buf0, stats64 + (size_t)3 * 64 * 512,
                                  bnG + 3 * HIDW, bnB + 3 * HIDW, batch, pool, pcnt);

  // ---- head ----
  k_head<<<NBATCH, 256, 0, stream>>>(pool, pcnt, Wv, bv, Wo, bo, fusW, fusB,
                                     p1W, p1b, p2W, p2b, out);
}